// Round 6
// baseline (660.951 us; speedup 1.0000x reference)
//
#include <hip/hip_runtime.h>
#include <hip/hip_bf16.h>

// GCN 2-layer forward. CSR pull-aggregation (one node per lane-group; round-4
// proved serializing nodes in the gather costs 3.4x — TLP is the currency).
// dis pre-scaled into h1/h2 rows; self-loops handled in-register (not in CSR).
// N=100000, F_IN=512, HID=128, C=40, E=1.6M

#define F_IN 512
#define HID  128
#define NC   40

typedef __attribute__((ext_vector_type(8))) short bf16x8;
typedef __attribute__((ext_vector_type(4))) float f32x4v;

__device__ __forceinline__ ushort f2bf(float f) {
    union { float f; unsigned u; } x; x.f = f;
    unsigned r = x.u + 0x7FFFu + ((x.u >> 16) & 1u);   // round-to-nearest-even
    return (ushort)(r >> 16);
}
__device__ __forceinline__ float bf2f(ushort u) {
    return __uint_as_float((unsigned)u << 16);
}

// ---------------- degree count (real edges only) ----------------
__global__ void count_deg(const int* __restrict__ dst, int E, unsigned* __restrict__ cnt) {
    int t = blockIdx.x * blockDim.x + threadIdx.x;
    if (t < E) atomicAdd(&cnt[dst[t]], 1u);
}

// ---------------- prefix sum over cnt -> offs (exclusive), fused dis ---------
__global__ __launch_bounds__(1024) void scan_block(const unsigned* __restrict__ cnt,
                                                   unsigned* __restrict__ offs,
                                                   unsigned* __restrict__ bsums,
                                                   float* __restrict__ dis, int N) {
    __shared__ unsigned s[1024];
    int tid = threadIdx.x;
    int i = blockIdx.x * 1024 + tid;
    unsigned v = (i < N) ? cnt[i] : 0u;
    if (i < N) dis[i] = rsqrtf((float)v + 1.0f);   // +1 = self loop
    s[tid] = v;
    __syncthreads();
    #pragma unroll
    for (int d = 1; d < 1024; d <<= 1) {
        unsigned t = (tid >= d) ? s[tid - d] : 0u;
        __syncthreads();
        s[tid] += t;
        __syncthreads();
    }
    if (i < N) offs[i] = s[tid] - v;
    if (tid == 1023) bsums[blockIdx.x] = s[1023];
}

__global__ __launch_bounds__(1024) void scan_bsums(unsigned* __restrict__ bsums, int nb) {
    __shared__ unsigned s[1024];
    int tid = threadIdx.x;
    unsigned v = (tid < nb) ? bsums[tid] : 0u;
    s[tid] = v;
    __syncthreads();
    #pragma unroll
    for (int d = 1; d < 1024; d <<= 1) {
        unsigned t = (tid >= d) ? s[tid - d] : 0u;
        __syncthreads();
        s[tid] += t;
        __syncthreads();
    }
    if (tid < nb) bsums[tid] = s[tid] - v;   // exclusive
}

__global__ __launch_bounds__(1024) void scan_add(unsigned* __restrict__ offs,
                                                 const unsigned* __restrict__ bsums,
                                                 int N, unsigned total) {
    int i = blockIdx.x * 1024 + threadIdx.x;
    if (i < N) offs[i] += bsums[blockIdx.x];
    if (i == 0) offs[N] = total;
}

// ---------------- CSR fill (real edges only) ----------------
__global__ void fill_csr(const int* __restrict__ src, const int* __restrict__ dst,
                         const unsigned* __restrict__ offs, unsigned* __restrict__ cursor,
                         int* __restrict__ col, int E) {
    int t = blockIdx.x * blockDim.x + threadIdx.x;
    if (t >= E) return;
    int s = src[t], d = dst[t];
    unsigned pos = offs[d] + atomicAdd(&cursor[d], 1u);
    col[pos] = s;
}

// ---------------- merged weight pack ----------------
// W1p: [s(16)][kb(4)][n(128)][j(8)], k = s*32+kb*8+j   (65536 elems)
// W2p: [ks(4)][kb(4)][n(48)][j(8)],  k = ks*32+kb*8+j  (6144 elems, n>=40 -> 0)
__global__ void packW(const float* __restrict__ W1, const float* __restrict__ W2,
                      ushort* __restrict__ W1p, ushort* __restrict__ W2p) {
    int t = blockIdx.x * 256 + threadIdx.x;
    if (t < 65536) {
        int j = t & 7, n = (t >> 3) & 127, kb = (t >> 10) & 3, s = t >> 12;
        int k = s * 32 + kb * 8 + j;
        W1p[t] = f2bf(W1[(size_t)k * HID + n]);
    } else {
        int q = t - 65536;
        if (q < 6144) {
            int j = q & 7;
            int i2 = q >> 3;
            int n = i2 % 48;
            int i3 = i2 / 48;
            int kb = i3 & 3, ks = i3 >> 2;
            int k = ks * 32 + kb * 8 + j;
            float v = (n < NC) ? W2[(size_t)k * NC + n] : 0.f;
            W2p[q] = f2bf(v);
        }
    }
}

// ------- GEMM1 MFMA: h1s[N,128] = (bf16(x) @ W1) * dis[row]  (bf16 out) -----
// 128-row tile, 4 waves. A fragments loaded DIRECTLY from global (each wave
// owns its rows — LDS sharing of A buys nothing). B tile (8 KB) double-
// buffered in LDS: 1 barrier per K-step.
__global__ __launch_bounds__(256) void gemm1_mfma(const float* __restrict__ A,
                                                  const ushort* __restrict__ Bp,
                                                  const float* __restrict__ dis,
                                                  ushort* __restrict__ C, int N) {
    __shared__ __align__(16) ushort Bs[2][4096];
    const int tid  = threadIdx.x;
    const int wave = tid >> 6;
    const int lane = tid & 63;
    const int quad = lane >> 4;
    const int mr   = lane & 15;
    const int bm   = blockIdx.x * 128;

    const int r0 = bm + wave * 32 + mr;
    const int r1 = r0 + 16;
    const bool ok0 = r0 < N, ok1 = r1 < N;
    const float* arow0 = A + (size_t)r0 * F_IN + quad * 8;
    const float* arow1 = A + (size_t)r1 * F_IN + quad * 8;

    f32x4v acc[2][8];
    #pragma unroll
    for (int i = 0; i < 2; i++)
        #pragma unroll
        for (int t = 0; t < 8; t++)
            acc[i][t] = (f32x4v){0.f, 0.f, 0.f, 0.f};

    // stage B s=0
    {
        const uint4* sp = (const uint4*)Bp;
        uint4* dp = (uint4*)Bs[0];
        dp[tid] = sp[tid];
        dp[tid + 256] = sp[tid + 256];
    }
    __syncthreads();

    for (int s = 0; s < 16; s++) {
        // prefetch next B tile into alternate buffer
        if (s < 15) {
            const uint4* sp = (const uint4*)(Bp + (size_t)(s + 1) * 4096);
            uint4* dp = (uint4*)Bs[(s + 1) & 1];
            dp[tid] = sp[tid];
            dp[tid + 256] = sp[tid + 256];
        }
        // A fragments direct from global, convert fp32->bf16 in-reg
        float4 z = make_float4(0.f, 0.f, 0.f, 0.f);
        float4 a0l = ok0 ? *(const float4*)(arow0 + s * 32)     : z;
        float4 a0h = ok0 ? *(const float4*)(arow0 + s * 32 + 4) : z;
        float4 a1l = ok1 ? *(const float4*)(arow1 + s * 32)     : z;
        float4 a1h = ok1 ? *(const float4*)(arow1 + s * 32 + 4) : z;
        __align__(16) ushort ta[8], tb[8];
        ta[0]=f2bf(a0l.x); ta[1]=f2bf(a0l.y); ta[2]=f2bf(a0l.z); ta[3]=f2bf(a0l.w);
        ta[4]=f2bf(a0h.x); ta[5]=f2bf(a0h.y); ta[6]=f2bf(a0h.z); ta[7]=f2bf(a0h.w);
        tb[0]=f2bf(a1l.x); tb[1]=f2bf(a1l.y); tb[2]=f2bf(a1l.z); tb[3]=f2bf(a1l.w);
        tb[4]=f2bf(a1h.x); tb[5]=f2bf(a1h.y); tb[6]=f2bf(a1h.z); tb[7]=f2bf(a1h.w);
        bf16x8 fa0 = *(const bf16x8*)ta;
        bf16x8 fa1 = *(const bf16x8*)tb;
        const ushort* bbase = Bs[s & 1] + quad * 1024;
        #pragma unroll
        for (int t = 0; t < 8; t++) {
            bf16x8 b = *(const bf16x8*)&bbase[(t * 16 + mr) * 8];
            acc[0][t] = __builtin_amdgcn_mfma_f32_16x16x32_bf16(fa0, b, acc[0][t], 0, 0, 0);
            acc[1][t] = __builtin_amdgcn_mfma_f32_16x16x32_bf16(fa1, b, acc[1][t], 0, 0, 0);
        }
        __syncthreads();
    }
    // epilogue: C/D layout col=lane&15, row=quad*4+reg; scale by dis[row]
    #pragma unroll
    for (int i = 0; i < 2; i++) {
        int row0 = bm + wave * 32 + i * 16 + quad * 4;
        #pragma unroll
        for (int rr = 0; rr < 4; rr++) {
            int row = row0 + rr;
            if (row < N) {
                float ds = dis[row];
                #pragma unroll
                for (int t = 0; t < 8; t++)
                    C[(size_t)row * HID + t * 16 + mr] = f2bf(acc[i][t][rr] * ds);
            }
        }
    }
}

// ------- agg1: one node per 16-lane group, uint4 gathers, x4 unroll ----------
// out[node] = dis[node] * (h1s[node] + sum_{s in N(node)} h1s[s])
__global__ __launch_bounds__(256) void agg1_k(const ushort* __restrict__ h,
                                              const int* __restrict__ col,
                                              const unsigned* __restrict__ offs,
                                              const float* __restrict__ dis,
                                              ushort* __restrict__ out, int N) {
    int node = blockIdx.x * 16 + (threadIdx.x >> 4);
    if (node >= N) return;
    int lane = threadIdx.x & 15;
    const size_t coff = (size_t)lane * 8;
    float a0[8], a1[8] = {}, a2[8] = {}, a3[8] = {};
    {   // self
        uint4 v = *(const uint4*)(h + (size_t)node * HID + coff);
        const ushort* u = (const ushort*)&v;
        #pragma unroll
        for (int j = 0; j < 8; j++) a0[j] = bf2f(u[j]);
    }
    unsigned p0 = offs[node], p1 = offs[node + 1];
    unsigned p = p0;
    for (; p + 4 <= p1; p += 4) {
        int s0 = col[p], s1 = col[p+1], s2 = col[p+2], s3 = col[p+3];
        uint4 v0 = *(const uint4*)(h + (size_t)s0 * HID + coff);
        uint4 v1 = *(const uint4*)(h + (size_t)s1 * HID + coff);
        uint4 v2 = *(const uint4*)(h + (size_t)s2 * HID + coff);
        uint4 v3 = *(const uint4*)(h + (size_t)s3 * HID + coff);
        const ushort* u0 = (const ushort*)&v0;
        const ushort* u1 = (const ushort*)&v1;
        const ushort* u2 = (const ushort*)&v2;
        const ushort* u3 = (const ushort*)&v3;
        #pragma unroll
        for (int j = 0; j < 8; j++) {
            a0[j] += bf2f(u0[j]); a1[j] += bf2f(u1[j]);
            a2[j] += bf2f(u2[j]); a3[j] += bf2f(u3[j]);
        }
    }
    for (; p < p1; ++p) {
        int s = col[p];
        uint4 v = *(const uint4*)(h + (size_t)s * HID + coff);
        const ushort* u = (const ushort*)&v;
        #pragma unroll
        for (int j = 0; j < 8; j++) a0[j] += bf2f(u[j]);
    }
    float dd = dis[node];
    __align__(16) ushort o[8];
    #pragma unroll
    for (int j = 0; j < 8; j++)
        o[j] = f2bf(((a0[j] + a1[j]) + (a2[j] + a3[j])) * dd);
    *(uint4*)(out + (size_t)node * HID + coff) = *(const uint4*)o;
}

// ------- GEMM2 MFMA: h2s[N,40] = (relu(agg1 + b1) @ W2) * dis[row] (bf16) ---
__global__ __launch_bounds__(256) void gemm2_mfma(const ushort* __restrict__ A,
                                                  const float* __restrict__ b1,
                                                  const ushort* __restrict__ W2p,
                                                  const float* __restrict__ dis,
                                                  ushort* __restrict__ h2, int N) {
    __shared__ __align__(16) ushort As[128 * 136];
    __shared__ __align__(16) ushort Bs[6144];
    const int tid = threadIdx.x;
    const int bm = blockIdx.x * 128;

    {
        const uint4* s4 = (const uint4*)W2p;
        uint4* d4 = (uint4*)Bs;
        #pragma unroll
        for (int i = 0; i < 3; i++) d4[tid + i * 256] = s4[tid + i * 256];
    }
    {
        const int r  = tid >> 1;
        const int hh = tid & 1;
        const int row = bm + r;
        const float* brow = b1 + hh * 64;
        if (row < N) {
            const ushort* arow = A + (size_t)row * HID + hh * 64;
            #pragma unroll
            for (int i = 0; i < 8; i++) {
                uint4 raw = *(const uint4*)(arow + i * 8);
                const ushort* u = (const ushort*)&raw;
                __align__(16) ushort tmp[8];
                #pragma unroll
                for (int j = 0; j < 8; j++)
                    tmp[j] = f2bf(fmaxf(bf2f(u[j]) + brow[i * 8 + j], 0.f));
                *(uint4*)&As[r * 136 + hh * 64 + i * 8] = *(const uint4*)tmp;
            }
        } else {
            #pragma unroll
            for (int i = 0; i < 8; i++) {
                uint4 zz = {0, 0, 0, 0};
                *(uint4*)&As[r * 136 + hh * 64 + i * 8] = zz;
            }
        }
    }
    __syncthreads();

    const int wave = tid >> 6;
    const int lane = tid & 63;
    const int quad = lane >> 4;
    const int mr   = lane & 15;
    f32x4v acc[2][3];
    #pragma unroll
    for (int i = 0; i < 2; i++)
        #pragma unroll
        for (int t = 0; t < 3; t++)
            acc[i][t] = (f32x4v){0.f, 0.f, 0.f, 0.f};
    #pragma unroll
    for (int ks = 0; ks < 4; ks++) {
        bf16x8 a0 = *(const bf16x8*)&As[(wave * 32 + mr) * 136 + ks * 32 + quad * 8];
        bf16x8 a1 = *(const bf16x8*)&As[(wave * 32 + 16 + mr) * 136 + ks * 32 + quad * 8];
        #pragma unroll
        for (int t = 0; t < 3; t++) {
            bf16x8 b = *(const bf16x8*)&Bs[((ks * 4 + quad) * 48 + t * 16 + mr) * 8];
            acc[0][t] = __builtin_amdgcn_mfma_f32_16x16x32_bf16(a0, b, acc[0][t], 0, 0, 0);
            acc[1][t] = __builtin_amdgcn_mfma_f32_16x16x32_bf16(a1, b, acc[1][t], 0, 0, 0);
        }
    }
    #pragma unroll
    for (int i = 0; i < 2; i++) {
        #pragma unroll
        for (int rr = 0; rr < 4; rr++) {
            int node = bm + wave * 32 + i * 16 + quad * 4 + rr;
            if (node < N) {
                float ds = dis[node];
                #pragma unroll
                for (int t = 0; t < 3; t++) {
                    int c = t * 16 + mr;
                    if (c < NC)
                        h2[(size_t)node * NC + c] = f2bf(acc[i][t][rr] * ds);
                }
            }
        }
    }
}

// ------- agg2 + b2 + log_softmax: one node per 8-lane group, 5 active lanes --
// logits = dis[node] * (h2s[node] + sum h2s[s]) + b2
__global__ __launch_bounds__(256) void agg2_ls(const ushort* __restrict__ h2,
                                               const int* __restrict__ col,
                                               const unsigned* __restrict__ offs,
                                               const float* __restrict__ dis,
                                               const float* __restrict__ b2,
                                               float* __restrict__ out, int N) {
    int node = blockIdx.x * 32 + (threadIdx.x >> 3);
    if (node >= N) return;
    int lane = threadIdx.x & 7;
    const bool act = lane < 5;
    const size_t coff = (size_t)lane * 8;
    float a[8] = {}, c[8] = {};
    if (act) {
        uint4 v = *(const uint4*)(h2 + (size_t)node * NC + coff);
        const ushort* u = (const ushort*)&v;
        #pragma unroll
        for (int j = 0; j < 8; j++) a[j] = bf2f(u[j]);
    }
    unsigned p0 = offs[node], p1 = offs[node + 1];
    unsigned p = p0;
    for (; p + 2 <= p1; p += 2) {
        int s0 = col[p], s1 = col[p + 1];
        if (act) {
            uint4 v0 = *(const uint4*)(h2 + (size_t)s0 * NC + coff);
            uint4 v1 = *(const uint4*)(h2 + (size_t)s1 * NC + coff);
            const ushort* u0 = (const ushort*)&v0;
            const ushort* u1 = (const ushort*)&v1;
            #pragma unroll
            for (int j = 0; j < 8; j++) { a[j] += bf2f(u0[j]); c[j] += bf2f(u1[j]); }
        }
    }
    for (; p < p1; ++p) {
        int s = col[p];
        if (act) {
            uint4 v = *(const uint4*)(h2 + (size_t)s * NC + coff);
            const ushort* u = (const ushort*)&v;
            #pragma unroll
            for (int j = 0; j < 8; j++) a[j] += bf2f(u[j]);
        }
    }
    float dd = dis[node];
    float l[8];
    float m = -1e30f;
    if (act) {
        #pragma unroll
        for (int j = 0; j < 8; j++) {
            l[j] = (a[j] + c[j]) * dd + b2[lane * 8 + j];
            m = fmaxf(m, l[j]);
        }
    }
    #pragma unroll
    for (int d = 1; d < 8; d <<= 1) m = fmaxf(m, __shfl_xor(m, d, 8));
    float s = 0.f;
    if (act) {
        #pragma unroll
        for (int j = 0; j < 8; j++) s += __expf(l[j] - m);
    }
    #pragma unroll
    for (int d = 1; d < 8; d <<= 1) s += __shfl_xor(s, d, 8);
    float lse = m + __logf(s);
    if (act) {
        float* op = out + (size_t)node * NC + lane * 8;
        *(float4*)op       = make_float4(l[0]-lse, l[1]-lse, l[2]-lse, l[3]-lse);
        *(float4*)(op + 4) = make_float4(l[4]-lse, l[5]-lse, l[6]-lse, l[7]-lse);
    }
}

extern "C" void kernel_launch(void* const* d_in, const int* in_sizes, int n_in,
                              void* d_out, int out_size, void* d_ws, size_t ws_size,
                              hipStream_t stream) {
    const float* x  = (const float*)d_in[0];
    const int*   ei = (const int*)d_in[1];
    const float* W1 = (const float*)d_in[2];
    const float* b1 = (const float*)d_in[3];
    const float* W2 = (const float*)d_in[4];
    const float* b2 = (const float*)d_in[5];
    float* out = (float*)d_out;

    const int N = in_sizes[0] / F_IN;     // 100000
    const int E = in_sizes[1] / 2;        // 1600000
    const int* src = ei;
    const int* dst = ei + E;

    // ---- workspace layout ----
    char* ws = (char*)d_ws;
    size_t o = 0;
    unsigned* cnt  = (unsigned*)(ws + o); o += (size_t)N * 4;
    unsigned* cur  = (unsigned*)(ws + o); o += (size_t)N * 4;   // contiguous w/ cnt
    float*    dis  = (float*)   (ws + o); o += (size_t)N * 4;
    unsigned* offs = (unsigned*)(ws + o); o += (size_t)(N + 4) * 4;
    unsigned* bsums= (unsigned*)(ws + o); o += 4096;
    int*      col  = (int*)     (ws + o); o += (size_t)E * 4;
    o = (o + 15) & ~(size_t)15;
    ushort*   W1p  = (ushort*)  (ws + o); o += (size_t)F_IN * HID * 2;   // 128 KB
    o = (o + 15) & ~(size_t)15;
    ushort*   W2p  = (ushort*)  (ws + o); o += 6144 * 2;                 // 12 KB
    o = (o + 15) & ~(size_t)15;
    ushort*   h1   = (ushort*)  (ws + o); o += (size_t)N * HID * 2;      // 25.6 MB
    o = (o + 15) & ~(size_t)15;
    ushort*   ag1  = (ushort*)  (ws + o); o += (size_t)N * HID * 2;      // 25.6 MB
    o = (o + 15) & ~(size_t)15;
    ushort*   h2   = (ushort*)  (ws + o); o += (size_t)N * NC * 2;       // 8 MB

    const int nb = (N + 1023) / 1024;

    // degree + CSR build (cnt and cur zeroed in one memset — contiguous)
    hipMemsetAsync(cnt, 0, (size_t)N * 8, stream);
    count_deg<<<(E + 255) / 256, 256, 0, stream>>>(dst, E, cnt);
    scan_block<<<nb, 1024, 0, stream>>>(cnt, offs, bsums, dis, N);
    scan_bsums<<<1, 1024, 0, stream>>>(bsums, nb);
    scan_add<<<nb, 1024, 0, stream>>>(offs, bsums, N, (unsigned)E);
    fill_csr<<<(E + 255) / 256, 256, 0, stream>>>(src, dst, offs, cur, col, E);

    // weight packs (merged)
    packW<<<(65536 + 6144 + 255) / 256, 256, 0, stream>>>(W1, W2, W1p, W2p);

    // layer 1
    gemm1_mfma<<<(N + 127) / 128, 256, 0, stream>>>(x, W1p, dis, h1, N);
    agg1_k<<<(N + 15) / 16, 256, 0, stream>>>(h1, col, offs, dis, ag1, N);

    // layer 2
    gemm2_mfma<<<(N + 127) / 128, 256, 0, stream>>>(ag1, b1, W2p, dis, h2, N);
    agg2_ls<<<(N + 31) / 32, 256, 0, stream>>>(h2, col, offs, dis, b2, out, N);
}

// Round 7
// 636.040 us; speedup vs baseline: 1.0392x; 1.0392x over previous
//
#include <hip/hip_runtime.h>
#include <hip/hip_bf16.h>

// GCN 2-layer forward. CSR pull-aggregation (one node per lane-group; round-4
// proved serializing nodes in the gather costs 3.4x — TLP is the currency).
// Round-6 proved direct-global A fragments without occupancy/pipelining is
// latency-bound (Occ 24%, all pipes idle). gemm1 now: 64-row tiles + double-
// buffered LDS A+B with software-pipelined staging.
// N=100000, F_IN=512, HID=128, C=40, E=1.6M

#define F_IN 512
#define HID  128
#define NC   40

typedef __attribute__((ext_vector_type(8))) short bf16x8;
typedef __attribute__((ext_vector_type(4))) float f32x4v;

__device__ __forceinline__ ushort f2bf(float f) {
    union { float f; unsigned u; } x; x.f = f;
    unsigned r = x.u + 0x7FFFu + ((x.u >> 16) & 1u);   // round-to-nearest-even
    return (ushort)(r >> 16);
}
__device__ __forceinline__ float bf2f(ushort u) {
    return __uint_as_float((unsigned)u << 16);
}

// ---------------- degree count (real edges only) ----------------
__global__ void count_deg(const int* __restrict__ dst, int E, unsigned* __restrict__ cnt) {
    int t = blockIdx.x * blockDim.x + threadIdx.x;
    if (t < E) atomicAdd(&cnt[dst[t]], 1u);
}

// ---------------- prefix sum over cnt -> offs (exclusive), fused dis ---------
__global__ __launch_bounds__(1024) void scan_block(const unsigned* __restrict__ cnt,
                                                   unsigned* __restrict__ offs,
                                                   unsigned* __restrict__ bsums,
                                                   float* __restrict__ dis, int N) {
    __shared__ unsigned s[1024];
    int tid = threadIdx.x;
    int i = blockIdx.x * 1024 + tid;
    unsigned v = (i < N) ? cnt[i] : 0u;
    if (i < N) dis[i] = rsqrtf((float)v + 1.0f);   // +1 = self loop
    s[tid] = v;
    __syncthreads();
    #pragma unroll
    for (int d = 1; d < 1024; d <<= 1) {
        unsigned t = (tid >= d) ? s[tid - d] : 0u;
        __syncthreads();
        s[tid] += t;
        __syncthreads();
    }
    if (i < N) offs[i] = s[tid] - v;
    if (tid == 1023) bsums[blockIdx.x] = s[1023];
}

__global__ __launch_bounds__(1024) void scan_bsums(unsigned* __restrict__ bsums, int nb) {
    __shared__ unsigned s[1024];
    int tid = threadIdx.x;
    unsigned v = (tid < nb) ? bsums[tid] : 0u;
    s[tid] = v;
    __syncthreads();
    #pragma unroll
    for (int d = 1; d < 1024; d <<= 1) {
        unsigned t = (tid >= d) ? s[tid - d] : 0u;
        __syncthreads();
        s[tid] += t;
        __syncthreads();
    }
    if (tid < nb) bsums[tid] = s[tid] - v;   // exclusive
}

__global__ __launch_bounds__(1024) void scan_add(unsigned* __restrict__ offs,
                                                 const unsigned* __restrict__ bsums,
                                                 int N, unsigned total) {
    int i = blockIdx.x * 1024 + threadIdx.x;
    if (i < N) offs[i] += bsums[blockIdx.x];
    if (i == 0) offs[N] = total;
}

// ---------------- CSR fill (real edges only) ----------------
__global__ void fill_csr(const int* __restrict__ src, const int* __restrict__ dst,
                         const unsigned* __restrict__ offs, unsigned* __restrict__ cursor,
                         int* __restrict__ col, int E) {
    int t = blockIdx.x * blockDim.x + threadIdx.x;
    if (t >= E) return;
    int s = src[t], d = dst[t];
    unsigned pos = offs[d] + atomicAdd(&cursor[d], 1u);
    col[pos] = s;
}

// ---------------- merged weight pack ----------------
// W1p: [s(16)][kb(4)][n(128)][j(8)], k = s*32+kb*8+j   (65536 elems)
// W2p: [ks(4)][kb(4)][n(48)][j(8)],  k = ks*32+kb*8+j  (6144 elems, n>=40 -> 0)
__global__ void packW(const float* __restrict__ W1, const float* __restrict__ W2,
                      ushort* __restrict__ W1p, ushort* __restrict__ W2p) {
    int t = blockIdx.x * 256 + threadIdx.x;
    if (t < 65536) {
        int j = t & 7, n = (t >> 3) & 127, kb = (t >> 10) & 3, s = t >> 12;
        int k = s * 32 + kb * 8 + j;
        W1p[t] = f2bf(W1[(size_t)k * HID + n]);
    } else {
        int q = t - 65536;
        if (q < 6144) {
            int j = q & 7;
            int i2 = q >> 3;
            int n = i2 % 48;
            int i3 = i2 / 48;
            int kb = i3 & 3, ks = i3 >> 2;
            int k = ks * 32 + kb * 8 + j;
            float v = (n < NC) ? W2[(size_t)k * NC + n] : 0.f;
            W2p[q] = f2bf(v);
        }
    }
}

// ------- GEMM1 MFMA: h1s[N,128] = (bf16(x) @ W1) * dis[row]  (bf16 out) -----
// 64-row tile (1563 blocks -> ~6 blocks/CU for TLP), 4 waves, each wave 16
// rows x 128 cols (8 MFMA frags). A+B double-buffered in LDS; staging loads
// for step s+1 issued before MFMAs of step s (software pipeline, 1 barrier).
__global__ __launch_bounds__(256) void gemm1_mfma(const float* __restrict__ A,
                                                  const ushort* __restrict__ Bp,
                                                  const float* __restrict__ dis,
                                                  ushort* __restrict__ C, int N) {
    __shared__ __align__(16) ushort As[2][64 * 40];   // 5 KB each, pad stride 40
    __shared__ __align__(16) ushort Bs[2][4096];      // 8 KB each
    const int tid  = threadIdx.x;
    const int wave = tid >> 6;
    const int lane = tid & 63;
    const int quad = lane >> 4;
    const int mr   = lane & 15;
    const int bm   = blockIdx.x * 64;

    // staging map: thread t -> row sr (0..63), col chunk sq (0..3) of 8 floats
    const int sr = tid >> 2;
    const int sq = tid & 3;
    const bool srow_ok = (bm + sr) < N;
    const float* aptr = A + (size_t)(bm + sr) * F_IN + sq * 8;

    f32x4v acc[8];
    #pragma unroll
    for (int t = 0; t < 8; t++) acc[t] = (f32x4v){0.f, 0.f, 0.f, 0.f};

    float4 av0, av1;
    uint4  bv0, bv1;
    const float4 z4 = make_float4(0.f, 0.f, 0.f, 0.f);

    // ---- preload step 0 ----
    av0 = srow_ok ? *(const float4*)(aptr)     : z4;
    av1 = srow_ok ? *(const float4*)(aptr + 4) : z4;
    bv0 = ((const uint4*)Bp)[tid];
    bv1 = ((const uint4*)Bp)[tid + 256];
    {
        __align__(16) ushort ta[8];
        ta[0]=f2bf(av0.x); ta[1]=f2bf(av0.y); ta[2]=f2bf(av0.z); ta[3]=f2bf(av0.w);
        ta[4]=f2bf(av1.x); ta[5]=f2bf(av1.y); ta[6]=f2bf(av1.z); ta[7]=f2bf(av1.w);
        *(uint4*)&As[0][sr * 40 + sq * 8] = *(const uint4*)ta;
        ((uint4*)Bs[0])[tid] = bv0;
        ((uint4*)Bs[0])[tid + 256] = bv1;
    }
    __syncthreads();

    for (int s = 0; s < 16; s++) {
        // issue global loads for step s+1 (latency covered by MFMAs below)
        if (s < 15) {
            av0 = srow_ok ? *(const float4*)(aptr + (s + 1) * 32)     : z4;
            av1 = srow_ok ? *(const float4*)(aptr + (s + 1) * 32 + 4) : z4;
            const uint4* bp = (const uint4*)(Bp + (size_t)(s + 1) * 4096);
            bv0 = bp[tid];
            bv1 = bp[tid + 256];
        }
        // compute step s from LDS buffer s&1
        {
            const ushort* ab = As[s & 1];
            const ushort* bb = Bs[s & 1] + quad * 1024;
            bf16x8 a = *(const bf16x8*)&ab[(wave * 16 + mr) * 40 + quad * 8];
            #pragma unroll
            for (int t = 0; t < 8; t++) {
                bf16x8 b = *(const bf16x8*)&bb[(t * 16 + mr) * 8];
                acc[t] = __builtin_amdgcn_mfma_f32_16x16x32_bf16(a, b, acc[t], 0, 0, 0);
            }
        }
        // stage s+1 into the other buffer
        if (s < 15) {
            __align__(16) ushort ta[8];
            ta[0]=f2bf(av0.x); ta[1]=f2bf(av0.y); ta[2]=f2bf(av0.z); ta[3]=f2bf(av0.w);
            ta[4]=f2bf(av1.x); ta[5]=f2bf(av1.y); ta[6]=f2bf(av1.z); ta[7]=f2bf(av1.w);
            int nb = (s + 1) & 1;
            *(uint4*)&As[nb][sr * 40 + sq * 8] = *(const uint4*)ta;
            ((uint4*)Bs[nb])[tid] = bv0;
            ((uint4*)Bs[nb])[tid + 256] = bv1;
        }
        __syncthreads();
    }

    // epilogue: C/D layout col=mr, row=quad*4+reg; scale by dis[row]
    #pragma unroll
    for (int rr = 0; rr < 4; rr++) {
        int row = bm + wave * 16 + quad * 4 + rr;
        if (row < N) {
            float ds = dis[row];
            #pragma unroll
            for (int t = 0; t < 8; t++)
                C[(size_t)row * HID + t * 16 + mr] = f2bf(acc[t][rr] * ds);
        }
    }
}

// ------- agg1: one node per 16-lane group, uint4 gathers, x8 unroll ----------
// out[node] = dis[node] * (h1s[node] + sum_{s in N(node)} h1s[s])
__global__ __launch_bounds__(256) void agg1_k(const ushort* __restrict__ h,
                                              const int* __restrict__ col,
                                              const unsigned* __restrict__ offs,
                                              const float* __restrict__ dis,
                                              ushort* __restrict__ out, int N) {
    int node = blockIdx.x * 16 + (threadIdx.x >> 4);
    if (node >= N) return;
    int lane = threadIdx.x & 15;
    const size_t coff = (size_t)lane * 8;
    float a[8];
    {   // self
        uint4 v = *(const uint4*)(h + (size_t)node * HID + coff);
        const ushort* u = (const ushort*)&v;
        #pragma unroll
        for (int j = 0; j < 8; j++) a[j] = bf2f(u[j]);
    }
    unsigned p0 = offs[node], p1 = offs[node + 1];
    unsigned p = p0;
    for (; p + 8 <= p1; p += 8) {
        int s0 = col[p],   s1 = col[p+1], s2 = col[p+2], s3 = col[p+3];
        int s4 = col[p+4], s5 = col[p+5], s6 = col[p+6], s7 = col[p+7];
        uint4 v0 = *(const uint4*)(h + (size_t)s0 * HID + coff);
        uint4 v1 = *(const uint4*)(h + (size_t)s1 * HID + coff);
        uint4 v2 = *(const uint4*)(h + (size_t)s2 * HID + coff);
        uint4 v3 = *(const uint4*)(h + (size_t)s3 * HID + coff);
        uint4 v4 = *(const uint4*)(h + (size_t)s4 * HID + coff);
        uint4 v5 = *(const uint4*)(h + (size_t)s5 * HID + coff);
        uint4 v6 = *(const uint4*)(h + (size_t)s6 * HID + coff);
        uint4 v7 = *(const uint4*)(h + (size_t)s7 * HID + coff);
        const ushort* u0 = (const ushort*)&v0;
        const ushort* u1 = (const ushort*)&v1;
        const ushort* u2 = (const ushort*)&v2;
        const ushort* u3 = (const ushort*)&v3;
        const ushort* u4 = (const ushort*)&v4;
        const ushort* u5 = (const ushort*)&v5;
        const ushort* u6 = (const ushort*)&v6;
        const ushort* u7 = (const ushort*)&v7;
        #pragma unroll
        for (int j = 0; j < 8; j++) {
            float t0 = bf2f(u0[j]) + bf2f(u1[j]);
            float t1 = bf2f(u2[j]) + bf2f(u3[j]);
            float t2 = bf2f(u4[j]) + bf2f(u5[j]);
            float t3 = bf2f(u6[j]) + bf2f(u7[j]);
            a[j] += (t0 + t1) + (t2 + t3);
        }
    }
    for (; p < p1; ++p) {
        int s = col[p];
        uint4 v = *(const uint4*)(h + (size_t)s * HID + coff);
        const ushort* u = (const ushort*)&v;
        #pragma unroll
        for (int j = 0; j < 8; j++) a[j] += bf2f(u[j]);
    }
    float dd = dis[node];
    __align__(16) ushort o[8];
    #pragma unroll
    for (int j = 0; j < 8; j++) o[j] = f2bf(a[j] * dd);
    *(uint4*)(out + (size_t)node * HID + coff) = *(const uint4*)o;
}

// ------- GEMM2 MFMA: h2s[N,40] = (relu(agg1 + b1) @ W2) * dis[row] (bf16) ---
__global__ __launch_bounds__(256) void gemm2_mfma(const ushort* __restrict__ A,
                                                  const float* __restrict__ b1,
                                                  const ushort* __restrict__ W2p,
                                                  const float* __restrict__ dis,
                                                  ushort* __restrict__ h2, int N) {
    __shared__ __align__(16) ushort As[128 * 136];
    __shared__ __align__(16) ushort Bs[6144];
    const int tid = threadIdx.x;
    const int bm = blockIdx.x * 128;

    {
        const uint4* s4 = (const uint4*)W2p;
        uint4* d4 = (uint4*)Bs;
        #pragma unroll
        for (int i = 0; i < 3; i++) d4[tid + i * 256] = s4[tid + i * 256];
    }
    {
        const int r  = tid >> 1;
        const int hh = tid & 1;
        const int row = bm + r;
        const float* brow = b1 + hh * 64;
        if (row < N) {
            const ushort* arow = A + (size_t)row * HID + hh * 64;
            #pragma unroll
            for (int i = 0; i < 8; i++) {
                uint4 raw = *(const uint4*)(arow + i * 8);
                const ushort* u = (const ushort*)&raw;
                __align__(16) ushort tmp[8];
                #pragma unroll
                for (int j = 0; j < 8; j++)
                    tmp[j] = f2bf(fmaxf(bf2f(u[j]) + brow[i * 8 + j], 0.f));
                *(uint4*)&As[r * 136 + hh * 64 + i * 8] = *(const uint4*)tmp;
            }
        } else {
            #pragma unroll
            for (int i = 0; i < 8; i++) {
                uint4 zz = {0, 0, 0, 0};
                *(uint4*)&As[r * 136 + hh * 64 + i * 8] = zz;
            }
        }
    }
    __syncthreads();

    const int wave = tid >> 6;
    const int lane = tid & 63;
    const int quad = lane >> 4;
    const int mr   = lane & 15;
    f32x4v acc[2][3];
    #pragma unroll
    for (int i = 0; i < 2; i++)
        #pragma unroll
        for (int t = 0; t < 3; t++)
            acc[i][t] = (f32x4v){0.f, 0.f, 0.f, 0.f};
    #pragma unroll
    for (int ks = 0; ks < 4; ks++) {
        bf16x8 a0 = *(const bf16x8*)&As[(wave * 32 + mr) * 136 + ks * 32 + quad * 8];
        bf16x8 a1 = *(const bf16x8*)&As[(wave * 32 + 16 + mr) * 136 + ks * 32 + quad * 8];
        #pragma unroll
        for (int t = 0; t < 3; t++) {
            bf16x8 b = *(const bf16x8*)&Bs[((ks * 4 + quad) * 48 + t * 16 + mr) * 8];
            acc[0][t] = __builtin_amdgcn_mfma_f32_16x16x32_bf16(a0, b, acc[0][t], 0, 0, 0);
            acc[1][t] = __builtin_amdgcn_mfma_f32_16x16x32_bf16(a1, b, acc[1][t], 0, 0, 0);
        }
    }
    #pragma unroll
    for (int i = 0; i < 2; i++) {
        #pragma unroll
        for (int rr = 0; rr < 4; rr++) {
            int node = bm + wave * 32 + i * 16 + quad * 4 + rr;
            if (node < N) {
                float ds = dis[node];
                #pragma unroll
                for (int t = 0; t < 3; t++) {
                    int c = t * 16 + mr;
                    if (c < NC)
                        h2[(size_t)node * NC + c] = f2bf(acc[i][t][rr] * ds);
                }
            }
        }
    }
}

// ------- agg2 + b2 + log_softmax: one node per 8-lane group, 5 active lanes --
// logits = dis[node] * (h2s[node] + sum h2s[s]) + b2
__global__ __launch_bounds__(256) void agg2_ls(const ushort* __restrict__ h2,
                                               const int* __restrict__ col,
                                               const unsigned* __restrict__ offs,
                                               const float* __restrict__ dis,
                                               const float* __restrict__ b2,
                                               float* __restrict__ out, int N) {
    int node = blockIdx.x * 32 + (threadIdx.x >> 3);
    if (node >= N) return;
    int lane = threadIdx.x & 7;
    const bool act = lane < 5;
    const size_t coff = (size_t)lane * 8;
    float a[8] = {};
    if (act) {
        uint4 v = *(const uint4*)(h2 + (size_t)node * NC + coff);
        const ushort* u = (const ushort*)&v;
        #pragma unroll
        for (int j = 0; j < 8; j++) a[j] = bf2f(u[j]);
    }
    unsigned p0 = offs[node], p1 = offs[node + 1];
    unsigned p = p0;
    for (; p + 4 <= p1; p += 4) {
        int s0 = col[p], s1 = col[p + 1], s2 = col[p + 2], s3 = col[p + 3];
        if (act) {
            uint4 v0 = *(const uint4*)(h2 + (size_t)s0 * NC + coff);
            uint4 v1 = *(const uint4*)(h2 + (size_t)s1 * NC + coff);
            uint4 v2 = *(const uint4*)(h2 + (size_t)s2 * NC + coff);
            uint4 v3 = *(const uint4*)(h2 + (size_t)s3 * NC + coff);
            const ushort* u0 = (const ushort*)&v0;
            const ushort* u1 = (const ushort*)&v1;
            const ushort* u2 = (const ushort*)&v2;
            const ushort* u3 = (const ushort*)&v3;
            #pragma unroll
            for (int j = 0; j < 8; j++)
                a[j] += (bf2f(u0[j]) + bf2f(u1[j])) + (bf2f(u2[j]) + bf2f(u3[j]));
        }
    }
    for (; p < p1; ++p) {
        int s = col[p];
        if (act) {
            uint4 v = *(const uint4*)(h2 + (size_t)s * NC + coff);
            const ushort* u = (const ushort*)&v;
            #pragma unroll
            for (int j = 0; j < 8; j++) a[j] += bf2f(u[j]);
        }
    }
    float dd = dis[node];
    float l[8];
    float m = -1e30f;
    if (act) {
        #pragma unroll
        for (int j = 0; j < 8; j++) {
            l[j] = a[j] * dd + b2[lane * 8 + j];
            m = fmaxf(m, l[j]);
        }
    }
    #pragma unroll
    for (int d = 1; d < 8; d <<= 1) m = fmaxf(m, __shfl_xor(m, d, 8));
    float s = 0.f;
    if (act) {
        #pragma unroll
        for (int j = 0; j < 8; j++) s += __expf(l[j] - m);
    }
    #pragma unroll
    for (int d = 1; d < 8; d <<= 1) s += __shfl_xor(s, d, 8);
    float lse = m + __logf(s);
    if (act) {
        float* op = out + (size_t)node * NC + lane * 8;
        *(float4*)op       = make_float4(l[0]-lse, l[1]-lse, l[2]-lse, l[3]-lse);
        *(float4*)(op + 4) = make_float4(l[4]-lse, l[5]-lse, l[6]-lse, l[7]-lse);
    }
}

extern "C" void kernel_launch(void* const* d_in, const int* in_sizes, int n_in,
                              void* d_out, int out_size, void* d_ws, size_t ws_size,
                              hipStream_t stream) {
    const float* x  = (const float*)d_in[0];
    const int*   ei = (const int*)d_in[1];
    const float* W1 = (const float*)d_in[2];
    const float* b1 = (const float*)d_in[3];
    const float* W2 = (const float*)d_in[4];
    const float* b2 = (const float*)d_in[5];
    float* out = (float*)d_out;

    const int N = in_sizes[0] / F_IN;     // 100000
    const int E = in_sizes[1] / 2;        // 1600000
    const int* src = ei;
    const int* dst = ei + E;

    // ---- workspace layout ----
    char* ws = (char*)d_ws;
    size_t o = 0;
    unsigned* cnt  = (unsigned*)(ws + o); o += (size_t)N * 4;
    unsigned* cur  = (unsigned*)(ws + o); o += (size_t)N * 4;   // contiguous w/ cnt
    float*    dis  = (float*)   (ws + o); o += (size_t)N * 4;
    unsigned* offs = (unsigned*)(ws + o); o += (size_t)(N + 4) * 4;
    unsigned* bsums= (unsigned*)(ws + o); o += 4096;
    int*      col  = (int*)     (ws + o); o += (size_t)E * 4;
    o = (o + 15) & ~(size_t)15;
    ushort*   W1p  = (ushort*)  (ws + o); o += (size_t)F_IN * HID * 2;   // 128 KB
    o = (o + 15) & ~(size_t)15;
    ushort*   W2p  = (ushort*)  (ws + o); o += 6144 * 2;                 // 12 KB
    o = (o + 15) & ~(size_t)15;
    ushort*   h1   = (ushort*)  (ws + o); o += (size_t)N * HID * 2;      // 25.6 MB
    o = (o + 15) & ~(size_t)15;
    ushort*   ag1  = (ushort*)  (ws + o); o += (size_t)N * HID * 2;      // 25.6 MB
    o = (o + 15) & ~(size_t)15;
    ushort*   h2   = (ushort*)  (ws + o); o += (size_t)N * NC * 2;       // 8 MB

    const int nb = (N + 1023) / 1024;

    // degree + CSR build (cnt and cur zeroed in one memset — contiguous)
    hipMemsetAsync(cnt, 0, (size_t)N * 8, stream);
    count_deg<<<(E + 255) / 256, 256, 0, stream>>>(dst, E, cnt);
    scan_block<<<nb, 1024, 0, stream>>>(cnt, offs, bsums, dis, N);
    scan_bsums<<<1, 1024, 0, stream>>>(bsums, nb);
    scan_add<<<nb, 1024, 0, stream>>>(offs, bsums, N, (unsigned)E);
    fill_csr<<<(E + 255) / 256, 256, 0, stream>>>(src, dst, offs, cur, col, E);

    // weight packs (merged)
    packW<<<(65536 + 6144 + 255) / 256, 256, 0, stream>>>(W1, W2, W1p, W2p);

    // layer 1
    gemm1_mfma<<<(N + 63) / 64, 256, 0, stream>>>(x, W1p, dis, h1, N);
    agg1_k<<<(N + 15) / 16, 256, 0, stream>>>(h1, col, offs, dis, ag1, N);

    // layer 2
    gemm2_mfma<<<(N + 127) / 128, 256, 0, stream>>>(ag1, b1, W2p, dis, h2, N);
    agg2_ls<<<(N + 31) / 32, 256, 0, stream>>>(h2, col, offs, dis, b2, out, N);
}